// Round 13
// baseline (185.139 us; speedup 1.0000x reference)
//
#include <hip/hip_runtime.h>
#include <hip/hip_bf16.h>

#define BSZ 4
#define CC 64
#define NN 4096
#define CN (CC*NN)        // 262144
#define BCN (BSZ*CN)      // 1048576

typedef __attribute__((ext_vector_type(4))) float    f4v;
typedef __attribute__((ext_vector_type(4))) int      i4v;
typedef __attribute__((ext_vector_type(2))) int      i2v;
typedef __attribute__((ext_vector_type(2))) unsigned u2v;
typedef __attribute__((ext_vector_type(8))) short    s8v;

// DPP cross-lane (VALU pipe): quad_perm within quads
#define DPP_F(x_, ctrl_) __builtin_bit_cast(float, \
    __builtin_amdgcn_update_dpp(0, __builtin_bit_cast(int, (float)(x_)), (ctrl_), 0xf, 0xf, true))
#define QP_X1 0xB1   // quad_perm [1,0,3,2]

__device__ __forceinline__ unsigned pack_bf16(float lo, float hi) {
    unsigned l = __builtin_bit_cast(unsigned, lo);
    unsigned h = __builtin_bit_cast(unsigned, hi);
    return (h & 0xFFFF0000u) | (l >> 16);
}
// single v_cvt_pk_bf16_f32 (RNE); __hip_bfloat162 is not trivially copyable,
// so extract the bits with memcpy instead of bit_cast.
__device__ __forceinline__ unsigned pack2(float lo, float hi) {
    float2 f2; f2.x = lo; f2.y = hi;
    __hip_bfloat162 h = __float22bfloat162_rn(f2);
    unsigned u;
    __builtin_memcpy(&u, &h, 4);
    return u;
}
__device__ __forceinline__ float blo(int d) {
    return __builtin_bit_cast(float, (unsigned)d << 16);
}
__device__ __forceinline__ float bhi(int d) {
    return __builtin_bit_cast(float, (unsigned)d & 0xFFFF0000u);
}

// ---------------------------------------------------------------------------
// K1: gram partials, 128-wide n-chunks. grid 256 = (i2:2, b:4, chunk:32).
// X staged transposed in LDS, 4x4 register tile per thread.
// Also zeroes the flash split-K counters (blocks 0..63) — safe: kernel
// boundaries between dependent dispatches act as device-scope release.
__global__ __launch_bounds__(256) void gram_k(const float* __restrict__ cnn,
                                              const float* __restrict__ vit,
                                              float* __restrict__ part,
                                              unsigned* __restrict__ cnt) {
    __shared__ __align__(16) float sXT[128*68];       // [n][c], pitch 68
    int t = threadIdx.x;
    int blk = blockIdx.x;
    if (blk < 64 && t == 0) cnt[blk] = 0;
    int ch = blk & 31, b = (blk >> 5) & 3, i2 = blk >> 7;
    const float* X = (i2 ? vit : cnn) + b * CN;
    int n0 = ch * 128;
#pragma unroll
    for (int j = 0; j < 8; j++) {
        int idx = t + j * 256;                        // 0..2047
        int c = idx >> 5, n4 = idx & 31;
        f4v val = *(const f4v*)&X[c * NN + n0 + n4 * 4];
        int base = (n4 * 4) * 68 + c;
        sXT[base]       = val[0];
        sXT[base + 68]  = val[1];
        sXT[base + 136] = val[2];
        sXT[base + 204] = val[3];
    }
    __syncthreads();
    int tc = (t & 15) * 4, td = (t >> 4) * 4;
    f4v acc[4];
#pragma unroll
    for (int i = 0; i < 4; i++) acc[i] = (f4v){0.f, 0.f, 0.f, 0.f};
    for (int k = 0; k < 128; k++) {
        f4v a  = *(const f4v*)&sXT[k * 68 + tc];
        f4v bb = *(const f4v*)&sXT[k * 68 + td];
#pragma unroll
        for (int i = 0; i < 4; i++) acc[i] += a[i] * bb;
    }
    float* dst = part + ch * 32768 + (i2 * 4 + b) * 4096;
#pragma unroll
    for (int i = 0; i < 4; i++) *(f4v*)&dst[(tc + i) * 64 + td] = acc[i];
}

// ---------------------------------------------------------------------------
// K2: reduce 32 gram partials + fused channel softmax (exp(min-x)/sum form).
__global__ void gred_k(const float* __restrict__ part, float* __restrict__ G) {
    int row = blockIdx.x;                             // 512 = 2*B*C
    int d = threadIdx.x;                              // 64
    float s = 0.f;
#pragma unroll 8
    for (int ch = 0; ch < 32; ch++) s += part[ch * 32768 + row * 64 + d];
    float mn = s;
#pragma unroll
    for (int off = 1; off < 64; off <<= 1) mn = fminf(mn, __shfl_xor(mn, off));
    float e = __expf(mn - s);
    float sm = e;
#pragma unroll
    for (int off = 1; off < 64; off <<= 1) sm += __shfl_xor(sm, off);
    G[row * 64 + d] = e / sm;
}

// ---------------------------------------------------------------------------
// K3: effective weights + bf16 MFMA-A-fragment pack. grid 20 = (b:4, tile:5).
// Weff = g*(W·A) + W (exact fold). tile0 rows = [Wq'(8); Wk'(8)], tiles1..4 =
// Wv' 16-row chunks.
__global__ __launch_bounds__(256) void weff_k(const float* __restrict__ G,
                                              const float* __restrict__ Wq,
                                              const float* __restrict__ Wk,
                                              const float* __restrict__ Wv,
                                              const float* __restrict__ gcnn,
                                              const float* __restrict__ gvit,
                                              ushort* __restrict__ WeffB) {
    __shared__ float sA[8192];                        // Gc | Gv  (A[d][c])
    __shared__ float sWt[1024];                       // this tile's 16x64 fp32
    int t = threadIdx.x;
    int b = blockIdx.x / 5, tile = blockIdx.x % 5;
    for (int i = t; i < 4096; i += 256) {
        sA[i]        = G[b * 4096 + i];
        sA[4096 + i] = G[(4 + b) * 4096 + i];
    }
    __syncthreads();
    float gc = *gcnn, gv = *gvit;
#pragma unroll
    for (int k = 0; k < 4; k++) {
        int idx = k * 256 + t;                        // 0..1023
        int r = idx >> 6, c = idx & 63;
        const float* Wrow; const float* A; float g;
        if (tile == 0) {
            if (r < 8) { Wrow = Wq + r * 64;       A = sA;        g = gc; }
            else       { Wrow = Wk + (r - 8) * 64; A = sA + 4096; g = gv; }
        } else         { Wrow = Wv + ((tile - 1) * 16 + r) * 64; A = sA + 4096; g = gv; }
        float s = 0.f;
#pragma unroll 8
        for (int d = 0; d < 64; d++) s += Wrow[d] * A[d * 64 + c];
        sWt[idx] = g * s + Wrow[c];
    }
    __syncthreads();
    if (t < 128) {
        int frag = t >> 6, lane = t & 63, m = lane & 15, q4 = lane >> 4;
        i4v o;
#pragma unroll
        for (int p = 0; p < 4; p++) {
            int c0 = frag * 32 + q4 * 8 + 2 * p;
            o[p] = (int)pack_bf16(sWt[m * 64 + c0], sWt[m * 64 + c0 + 1]);
        }
        *(i4v*)&WeffB[(size_t)(b * 10 + tile * 2 + frag) * 512 + lane * 8] = o;
    }
}

// ---------------------------------------------------------------------------
// K4: MFMA QKV projections. grid 256 = (b:4, nchunk:64). q is scaled by
// log2(e) so flash can use native v_exp_f32 (2^x) directly.
__global__ __launch_bounds__(256) void qkv_k(const float* __restrict__ cnn,
                                             const float* __restrict__ vit,
                                             const ushort* __restrict__ WeffB,
                                             const float* __restrict__ bq,
                                             const float* __restrict__ bk,
                                             const float* __restrict__ bv,
                                             ushort* __restrict__ qb, ushort* __restrict__ kb,
                                             ushort* __restrict__ vT) {
    int t = threadIdx.x;
    int b = blockIdx.x >> 6, n0 = (blockIdx.x & 63) * 64;
    int w = t >> 6, lane = t & 63, c15 = lane & 15, q4 = lane >> 4;
    int n = n0 + w * 16 + c15;
    const float LOG2E = 1.44269504f;

    s8v A[10];
    const ushort* WB = WeffB + (size_t)b * 5120 + lane * 8;
#pragma unroll
    for (int i = 0; i < 10; i++)
        A[i] = __builtin_bit_cast(s8v, *(const i4v*)(WB + (size_t)i * 512));

    s8v Bc[2], Bv[2];
#pragma unroll
    for (int f = 0; f < 2; f++) {
        i4v pc, pv;
#pragma unroll
        for (int p = 0; p < 4; p++) {
            int c0 = f * 32 + q4 * 8 + p * 2;
            size_t a0 = (size_t)b * CN + (size_t)c0 * NN + n;
            pc[p] = (int)pack_bf16(cnn[a0], cnn[a0 + NN]);
            pv[p] = (int)pack_bf16(vit[a0], vit[a0 + NN]);
        }
        Bc[f] = __builtin_bit_cast(s8v, pc);
        Bv[f] = __builtin_bit_cast(s8v, pv);
    }

    // q rows (scaled by log2e)
    f4v acc = *(const f4v*)(bq + (q4 & 1) * 4);
    acc = __builtin_amdgcn_mfma_f32_16x16x32_bf16(A[0], Bc[0], acc, 0, 0, 0);
    acc = __builtin_amdgcn_mfma_f32_16x16x32_bf16(A[1], Bc[1], acc, 0, 0, 0);
    if (q4 < 2) {
        unsigned d0 = pack_bf16(acc[0] * LOG2E, acc[1] * LOG2E);
        unsigned d1 = pack_bf16(acc[2] * LOG2E, acc[3] * LOG2E);
        unsigned long long v = ((unsigned long long)d1 << 32) | d0;
        *(unsigned long long*)&qb[(size_t)(b * NN + n) * 8 + q4 * 4] = v;
    }
    // k rows
    acc = *(const f4v*)(bk + (q4 & 1) * 4);
    acc = __builtin_amdgcn_mfma_f32_16x16x32_bf16(A[0], Bv[0], acc, 0, 0, 0);
    acc = __builtin_amdgcn_mfma_f32_16x16x32_bf16(A[1], Bv[1], acc, 0, 0, 0);
    if (q4 >= 2) {
        unsigned d0 = pack_bf16(acc[0], acc[1]), d1 = pack_bf16(acc[2], acc[3]);
        unsigned long long v = ((unsigned long long)d1 << 32) | d0;
        *(unsigned long long*)&kb[(size_t)(b * NN + n) * 8 + (q4 - 2) * 4] = v;
    }
    // v rows -> vT[b][c][n]
#pragma unroll
    for (int tile = 1; tile < 5; tile++) {
        acc = *(const f4v*)(bv + (tile - 1) * 16 + q4 * 4);
        acc = __builtin_amdgcn_mfma_f32_16x16x32_bf16(A[tile * 2],     Bv[0], acc, 0, 0, 0);
        acc = __builtin_amdgcn_mfma_f32_16x16x32_bf16(A[tile * 2 + 1], Bv[1], acc, 0, 0, 0);
#pragma unroll
        for (int r = 0; r < 4; r++) {
            float other = DPP_F(acc[r], QP_X1);
            unsigned pkd = (lane & 1) ? pack_bf16(other, acc[r])
                                      : pack_bf16(acc[r], other);
            if (!(lane & 1)) {
                int row = (tile - 1) * 16 + q4 * 4 + r;
                *(unsigned*)&vT[(size_t)(b * 64 + row) * NN + n] = pkd;
            }
        }
    }
}

// ---------------------------------------------------------------------------
// K5: MFMA flash + fused split-K combine (last-block-done pattern).
// Split-K x8, 64 q/wave, double-buffered pi-permuted LDS V staging (one
// barrier/kt). pOT partials bf16 [s][b][cg][n][4c]. After storing partials +
// __threadfence(), each block bumps a device-scope counter for its
// (b,qchunk) group; the 8th arrival combines all splits for its 256-q range
// and writes out = gamma*O/L + cnn. Counters zeroed by gram_k.
// grid 512 = (split:8, b:4, qchunk:16 of 256). p = exp2(S) (no max-rescale:
// scores O(0.1), shift-invariant softmax; split partials sum directly).
__global__ __launch_bounds__(256, 2) void flash_k(const ushort* __restrict__ qb,
                                                  const ushort* __restrict__ kb,
                                                  const ushort* __restrict__ vT,
                                                  ushort* __restrict__ pOT,
                                                  float* __restrict__ pl,
                                                  unsigned* __restrict__ cnt,
                                                  const float* __restrict__ cnn,
                                                  const float* __restrict__ gamma,
                                                  float* __restrict__ out) {
    __shared__ __align__(16) ushort Vlds[2 * 64 * 72]; // 18432 B
    __shared__ int lastflag;
    int t = threadIdx.x;
    int lane = t & 63, w = t >> 6;
    int c15 = lane & 15, q4 = lane >> 4;
    int blk = blockIdx.x;
    int s = blk >> 6, b = (blk >> 4) & 3, qc = blk & 15, q0 = qc * 256;

    s8v qB[4];
#pragma unroll
    for (int g = 0; g < 4; g++) {
        i4v qa = (i4v){0, 0, 0, 0};
        if (q4 == 0)
            qa = *(const i4v*)(qb + (size_t)(b * NN + q0 + w * 64 + g * 16 + c15) * 8);
        qB[g] = __builtin_bit_cast(s8v, qa);
    }

    f4v accO[4][4];
#pragma unroll
    for (int g = 0; g < 4; g++)
#pragma unroll
        for (int nt = 0; nt < 4; nt++) accO[g][nt] = (f4v){0.f, 0.f, 0.f, 0.f};
    float lacc[4] = {0.f, 0.f, 0.f, 0.f};

    const ushort* kbb = kb + (size_t)b * NN * 8 + (size_t)c15 * 8;

    // staging role: thread t covers V row r, 16-k chunk chk
    int r = t >> 2, chk = t & 3;
    const ushort* vsrc = vT + (size_t)(b * 64 + r) * NN + chk * 16;
    int vdstoff = r * 72 + 32 * (chk >> 1) + 4 * (chk & 1);
    int vreadoff = c15 * 72 + 8 * q4;

    int kbase = s * 512;
    // preload K and V for kt0
    i4v bk_cur[4];
#pragma unroll
    for (int nt = 0; nt < 4; nt++)
        bk_cur[nt] = *(const i4v*)(kbb + (size_t)(kbase + nt * 16) * 8);
    i4v v0 = *(const i4v*)(vsrc + kbase);
    i4v v1 = *(const i4v*)(vsrc + kbase + 8);

    for (int kt = 0; kt < 8; kt++) {
        int k0 = kbase + kt * 64;
        // scatter-write tile kt into permuted LDS buffer kt&1
        ushort* vd = Vlds + (kt & 1) * 4608 + vdstoff;
        *(i2v*)(vd + 0)  = (i2v){v0[0], v0[1]};
        *(i2v*)(vd + 8)  = (i2v){v0[2], v0[3]};
        *(i2v*)(vd + 16) = (i2v){v1[0], v1[1]};
        *(i2v*)(vd + 24) = (i2v){v1[2], v1[3]};
        __syncthreads();                               // writes visible

        // PV A-frags: one contiguous b128 per (F,nt), shared by all 4 g
        const ushort* vb = Vlds + (kt & 1) * 4608 + vreadoff;
        i4v vA[2][4];
#pragma unroll
        for (int F = 0; F < 2; F++)
#pragma unroll
            for (int nt = 0; nt < 4; nt++)
                vA[F][nt] = *(const i4v*)(vb + nt * 16 * 72 + 32 * F);

        // prefetch next kt's V (global, coalesced) and K (broadcast)
        i4v bk_nxt[4];
        if (kt < 7) {
            v0 = *(const i4v*)(vsrc + k0 + 64);
            v1 = *(const i4v*)(vsrc + k0 + 64 + 8);
#pragma unroll
            for (int nt = 0; nt < 4; nt++)
                bk_nxt[nt] = *(const i4v*)(kbb + (size_t)(k0 + 64 + nt * 16) * 8);
        }

        // process q-groups in pairs (bounds register pressure)
#pragma unroll
        for (int gp = 0; gp < 2; gp++) {
            f4v z = (f4v){0.f, 0.f, 0.f, 0.f};
            f4v S[2][4];
#pragma unroll
            for (int gg = 0; gg < 2; gg++)
#pragma unroll
                for (int nt = 0; nt < 4; nt++)
                    S[gg][nt] = __builtin_amdgcn_mfma_f32_16x16x32_bf16(
                        __builtin_bit_cast(s8v, bk_cur[nt]), qB[gp * 2 + gg],
                        z, 0, 0, 0);

            s8v Bp[2][2];
#pragma unroll
            for (int gg = 0; gg < 2; gg++) {
                f4v p[4];
                float ps = 0.f;
#pragma unroll
                for (int nt = 0; nt < 4; nt++)
#pragma unroll
                    for (int rr = 0; rr < 4; rr++) {
                        p[nt][rr] = __builtin_amdgcn_exp2f(S[gg][nt][rr]);
                        ps += p[nt][rr];
                    }
#pragma unroll
                for (int F = 0; F < 2; F++) {
                    i4v bp;
                    bp[0] = (int)pack2(p[2 * F][0],     p[2 * F][1]);
                    bp[1] = (int)pack2(p[2 * F][2],     p[2 * F][3]);
                    bp[2] = (int)pack2(p[2 * F + 1][0], p[2 * F + 1][1]);
                    bp[3] = (int)pack2(p[2 * F + 1][2], p[2 * F + 1][3]);
                    Bp[gg][F] = __builtin_bit_cast(s8v, bp);
                }
                lacc[gp * 2 + gg] += ps;
            }

            // PV: O^T[c][q] += V^T * P
#pragma unroll
            for (int F = 0; F < 2; F++)
#pragma unroll
                for (int gg = 0; gg < 2; gg++)
#pragma unroll
                    for (int nt = 0; nt < 4; nt++)
                        accO[gp * 2 + gg][nt] =
                            __builtin_amdgcn_mfma_f32_16x16x32_bf16(
                                __builtin_bit_cast(s8v, vA[F][nt]), Bp[gg][F],
                                accO[gp * 2 + gg][nt], 0, 0, 0);
        }
        if (kt < 7) {
#pragma unroll
            for (int nt = 0; nt < 4; nt++) bk_cur[nt] = bk_nxt[nt];
        }
    }

    // one-time cross-lane l reduction (lanes sharing q: xor 16, 32)
#pragma unroll
    for (int g = 0; g < 4; g++) {
        lacc[g] += __shfl_xor(lacc[g], 16);
        lacc[g] += __shfl_xor(lacc[g], 32);
    }

    // store bf16 O^T partials [s][b][cg][n][4c] (coalesced b64), l
#pragma unroll
    for (int g = 0; g < 4; g++) {
        int qg = q0 + w * 64 + g * 16 + c15;
#pragma unroll
        for (int nt = 0; nt < 4; nt++) {
            int cg = nt * 4 + q4;
            u2v d;
            d[0] = pack2(accO[g][nt][0], accO[g][nt][1]);
            d[1] = pack2(accO[g][nt][2], accO[g][nt][3]);
            *(u2v*)&pOT[((size_t)((s * 4 + b) * 16 + cg) * NN + qg) * 4] = d;
        }
        if (q4 == 0)
            pl[(size_t)(s * 4 + b) * NN + qg] = lacc[g];
    }

    // --- split-K tail combine: last block of the 8-split group does it ---
    __threadfence();                                   // device-scope release
    if (t == 0) lastflag = (int)atomicAdd(&cnt[b * 16 + qc], 1u);
    __syncthreads();
    if (lastflag != 7) return;
    __threadfence();                                   // acquire side

    float gsc = *gamma;
    int nq = t & 15, cl = t >> 4;
#pragma unroll
    for (int chunk = 0; chunk < 4; chunk++) {
        int n = q0 + chunk * 64 + nq * 4;
        f4v L = (f4v){0.f, 0.f, 0.f, 0.f};
#pragma unroll
        for (int ss = 0; ss < 8; ss++)
            L += *(const f4v*)&pl[(size_t)(ss * 4 + b) * NN + n];
        f4v rv;
#pragma unroll
        for (int j = 0; j < 4; j++) rv[j] = gsc / L[j];

        f4v Oc[4];
#pragma unroll
        for (int cc = 0; cc < 4; cc++) Oc[cc] = (f4v){0.f, 0.f, 0.f, 0.f};
#pragma unroll
        for (int ss = 0; ss < 8; ss++) {
            const ushort* src = pOT + ((size_t)((ss * 4 + b) * 16 + cl) * NN + n) * 4;
            i4v a  = *(const i4v*)src;
            i4v bb = *(const i4v*)(src + 8);
            Oc[0][0] += blo(a[0]);  Oc[1][0] += bhi(a[0]);
            Oc[2][0] += blo(a[1]);  Oc[3][0] += bhi(a[1]);
            Oc[0][1] += blo(a[2]);  Oc[1][1] += bhi(a[2]);
            Oc[2][1] += blo(a[3]);  Oc[3][1] += bhi(a[3]);
            Oc[0][2] += blo(bb[0]); Oc[1][2] += bhi(bb[0]);
            Oc[2][2] += blo(bb[1]); Oc[3][2] += bhi(bb[1]);
            Oc[0][3] += blo(bb[2]); Oc[1][3] += bhi(bb[2]);
            Oc[2][3] += blo(bb[3]); Oc[3][3] += bhi(bb[3]);
        }
#pragma unroll
        for (int cc = 0; cc < 4; cc++) {
            size_t gi = (size_t)(b * 64 + cl * 4 + cc) * NN + n;
            f4v cv = *(const f4v*)&cnn[gi];
            *(f4v*)&out[gi] = Oc[cc] * rv + cv;
        }
    }
}

// ---------------------------------------------------------------------------
extern "C" void kernel_launch(void* const* d_in, const int* in_sizes, int n_in,
                              void* d_out, int out_size, void* d_ws, size_t ws_size,
                              hipStream_t stream) {
    const float* cnn  = (const float*)d_in[0];
    const float* vit  = (const float*)d_in[1];
    const float* Wq   = (const float*)d_in[2];
    const float* bq   = (const float*)d_in[3];
    const float* Wk   = (const float*)d_in[4];
    const float* bk   = (const float*)d_in[5];
    const float* Wv   = (const float*)d_in[6];
    const float* bv   = (const float*)d_in[7];
    const float* gam  = (const float*)d_in[8];
    const float* gcnn = (const float*)d_in[9];
    const float* gvit = (const float*)d_in[10];
    float* out = (float*)d_out;

    float* ws = (float*)d_ws;
    // pOT (bf16, 8 splits, 16 MB) aliases part (first 4 MB) — part is
    // consumed by gred_k before flash_k writes pOT.
    ushort*   pOT   = (ushort*)ws;
    float*    part  = ws;
    float*    G     = ws + 8388608;            // 32768 f
    ushort*   WeffB = (ushort*)(ws + 8421376); // 20480 bf16
    ushort*   qb    = (ushort*)(ws + 8431616); // 131072 bf16
    ushort*   kb    = (ushort*)(ws + 8497152);
    ushort*   vT    = (ushort*)(ws + 8562688); // 1048576 bf16
    float*    pl    = ws + 9086976;            // 131072 f
    unsigned* cnt   = (unsigned*)(ws + 9218048); // 64 u32

    gram_k <<<256, 256, 0, stream>>>(cnn, vit, part, cnt);
    gred_k <<<512, 64,  0, stream>>>(part, G);
    weff_k <<<20,  256, 0, stream>>>(G, Wq, Wk, Wv, gcnn, gvit, WeffB);
    qkv_k  <<<256, 256, 0, stream>>>(cnn, vit, WeffB, bq, bk, bv, qb, kb, vT);
    flash_k<<<512, 256, 0, stream>>>(qb, kb, vT, pOT, pl, cnt, cnn, gam, out);
}

// Round 14
// 128.897 us; speedup vs baseline: 1.4363x; 1.4363x over previous
//
#include <hip/hip_runtime.h>
#include <hip/hip_bf16.h>

#define BSZ 4
#define CC 64
#define NN 4096
#define CN (CC*NN)        // 262144
#define BCN (BSZ*CN)      // 1048576

typedef __attribute__((ext_vector_type(4))) float    f4v;
typedef __attribute__((ext_vector_type(4))) int      i4v;
typedef __attribute__((ext_vector_type(2))) int      i2v;
typedef __attribute__((ext_vector_type(2))) unsigned u2v;
typedef __attribute__((ext_vector_type(8))) short    s8v;

// DPP cross-lane (VALU pipe): quad_perm within quads
#define DPP_F(x_, ctrl_) __builtin_bit_cast(float, \
    __builtin_amdgcn_update_dpp(0, __builtin_bit_cast(int, (float)(x_)), (ctrl_), 0xf, 0xf, true))
#define QP_X1 0xB1   // quad_perm [1,0,3,2]

__device__ __forceinline__ unsigned pack_bf16(float lo, float hi) {
    unsigned l = __builtin_bit_cast(unsigned, lo);
    unsigned h = __builtin_bit_cast(unsigned, hi);
    return (h & 0xFFFF0000u) | (l >> 16);
}
// single v_cvt_pk_bf16_f32 (RNE); __hip_bfloat162 is not trivially copyable,
// so extract the bits with memcpy instead of bit_cast.
__device__ __forceinline__ unsigned pack2(float lo, float hi) {
    float2 f2; f2.x = lo; f2.y = hi;
    __hip_bfloat162 h = __float22bfloat162_rn(f2);
    unsigned u;
    __builtin_memcpy(&u, &h, 4);
    return u;
}
__device__ __forceinline__ float blo(int d) {
    return __builtin_bit_cast(float, (unsigned)d << 16);
}
__device__ __forceinline__ float bhi(int d) {
    return __builtin_bit_cast(float, (unsigned)d & 0xFFFF0000u);
}

// ---------------------------------------------------------------------------
// K1: gram partials, 128-wide n-chunks. grid 256 = (i2:2, b:4, chunk:32).
// X staged transposed in LDS, 4x4 register tile per thread.
__global__ __launch_bounds__(256) void gram_k(const float* __restrict__ cnn,
                                              const float* __restrict__ vit,
                                              float* __restrict__ part) {
    __shared__ __align__(16) float sXT[128*68];       // [n][c], pitch 68
    int t = threadIdx.x;
    int blk = blockIdx.x;
    int ch = blk & 31, b = (blk >> 5) & 3, i2 = blk >> 7;
    const float* X = (i2 ? vit : cnn) + b * CN;
    int n0 = ch * 128;
#pragma unroll
    for (int j = 0; j < 8; j++) {
        int idx = t + j * 256;                        // 0..2047
        int c = idx >> 5, n4 = idx & 31;
        f4v val = *(const f4v*)&X[c * NN + n0 + n4 * 4];
        int base = (n4 * 4) * 68 + c;
        sXT[base]       = val[0];
        sXT[base + 68]  = val[1];
        sXT[base + 136] = val[2];
        sXT[base + 204] = val[3];
    }
    __syncthreads();
    int tc = (t & 15) * 4, td = (t >> 4) * 4;
    f4v acc[4];
#pragma unroll
    for (int i = 0; i < 4; i++) acc[i] = (f4v){0.f, 0.f, 0.f, 0.f};
    for (int k = 0; k < 128; k++) {
        f4v a  = *(const f4v*)&sXT[k * 68 + tc];
        f4v bb = *(const f4v*)&sXT[k * 68 + td];
#pragma unroll
        for (int i = 0; i < 4; i++) acc[i] += a[i] * bb;
    }
    float* dst = part + ch * 32768 + (i2 * 4 + b) * 4096;
#pragma unroll
    for (int i = 0; i < 4; i++) *(f4v*)&dst[(tc + i) * 64 + td] = acc[i];
}

// ---------------------------------------------------------------------------
// K2: reduce 32 gram partials + fused channel softmax (exp(min-x)/sum form).
__global__ void gred_k(const float* __restrict__ part, float* __restrict__ G) {
    int row = blockIdx.x;                             // 512 = 2*B*C
    int d = threadIdx.x;                              // 64
    float s = 0.f;
#pragma unroll 8
    for (int ch = 0; ch < 32; ch++) s += part[ch * 32768 + row * 64 + d];
    float mn = s;
#pragma unroll
    for (int off = 1; off < 64; off <<= 1) mn = fminf(mn, __shfl_xor(mn, off));
    float e = __expf(mn - s);
    float sm = e;
#pragma unroll
    for (int off = 1; off < 64; off <<= 1) sm += __shfl_xor(sm, off);
    G[row * 64 + d] = e / sm;
}

// ---------------------------------------------------------------------------
// K3: effective weights + bf16 MFMA-A-fragment pack. grid 20 = (b:4, tile:5).
// Weff = g*(W·A) + W (exact fold). tile0 rows = [Wq'(8); Wk'(8)], tiles1..4 =
// Wv' 16-row chunks.
__global__ __launch_bounds__(256) void weff_k(const float* __restrict__ G,
                                              const float* __restrict__ Wq,
                                              const float* __restrict__ Wk,
                                              const float* __restrict__ Wv,
                                              const float* __restrict__ gcnn,
                                              const float* __restrict__ gvit,
                                              ushort* __restrict__ WeffB) {
    __shared__ float sA[8192];                        // Gc | Gv  (A[d][c])
    __shared__ float sWt[1024];                       // this tile's 16x64 fp32
    int t = threadIdx.x;
    int b = blockIdx.x / 5, tile = blockIdx.x % 5;
    for (int i = t; i < 4096; i += 256) {
        sA[i]        = G[b * 4096 + i];
        sA[4096 + i] = G[(4 + b) * 4096 + i];
    }
    __syncthreads();
    float gc = *gcnn, gv = *gvit;
#pragma unroll
    for (int k = 0; k < 4; k++) {
        int idx = k * 256 + t;                        // 0..1023
        int r = idx >> 6, c = idx & 63;
        const float* Wrow; const float* A; float g;
        if (tile == 0) {
            if (r < 8) { Wrow = Wq + r * 64;       A = sA;        g = gc; }
            else       { Wrow = Wk + (r - 8) * 64; A = sA + 4096; g = gv; }
        } else         { Wrow = Wv + ((tile - 1) * 16 + r) * 64; A = sA + 4096; g = gv; }
        float s = 0.f;
#pragma unroll 8
        for (int d = 0; d < 64; d++) s += Wrow[d] * A[d * 64 + c];
        sWt[idx] = g * s + Wrow[c];
    }
    __syncthreads();
    if (t < 128) {
        int frag = t >> 6, lane = t & 63, m = lane & 15, q4 = lane >> 4;
        i4v o;
#pragma unroll
        for (int p = 0; p < 4; p++) {
            int c0 = frag * 32 + q4 * 8 + 2 * p;
            o[p] = (int)pack_bf16(sWt[m * 64 + c0], sWt[m * 64 + c0 + 1]);
        }
        *(i4v*)&WeffB[(size_t)(b * 10 + tile * 2 + frag) * 512 + lane * 8] = o;
    }
}

// ---------------------------------------------------------------------------
// K4: MFMA QKV projections. grid 256 = (b:4, nchunk:64). q is scaled by
// log2(e) so flash can use native v_exp_f32 (2^x) directly.
__global__ __launch_bounds__(256) void qkv_k(const float* __restrict__ cnn,
                                             const float* __restrict__ vit,
                                             const ushort* __restrict__ WeffB,
                                             const float* __restrict__ bq,
                                             const float* __restrict__ bk,
                                             const float* __restrict__ bv,
                                             ushort* __restrict__ qb, ushort* __restrict__ kb,
                                             ushort* __restrict__ vT) {
    int t = threadIdx.x;
    int b = blockIdx.x >> 6, n0 = (blockIdx.x & 63) * 64;
    int w = t >> 6, lane = t & 63, c15 = lane & 15, q4 = lane >> 4;
    int n = n0 + w * 16 + c15;
    const float LOG2E = 1.44269504f;

    s8v A[10];
    const ushort* WB = WeffB + (size_t)b * 5120 + lane * 8;
#pragma unroll
    for (int i = 0; i < 10; i++)
        A[i] = __builtin_bit_cast(s8v, *(const i4v*)(WB + (size_t)i * 512));

    s8v Bc[2], Bv[2];
#pragma unroll
    for (int f = 0; f < 2; f++) {
        i4v pc, pv;
#pragma unroll
        for (int p = 0; p < 4; p++) {
            int c0 = f * 32 + q4 * 8 + p * 2;
            size_t a0 = (size_t)b * CN + (size_t)c0 * NN + n;
            pc[p] = (int)pack_bf16(cnn[a0], cnn[a0 + NN]);
            pv[p] = (int)pack_bf16(vit[a0], vit[a0 + NN]);
        }
        Bc[f] = __builtin_bit_cast(s8v, pc);
        Bv[f] = __builtin_bit_cast(s8v, pv);
    }

    // q rows (scaled by log2e)
    f4v acc = *(const f4v*)(bq + (q4 & 1) * 4);
    acc = __builtin_amdgcn_mfma_f32_16x16x32_bf16(A[0], Bc[0], acc, 0, 0, 0);
    acc = __builtin_amdgcn_mfma_f32_16x16x32_bf16(A[1], Bc[1], acc, 0, 0, 0);
    if (q4 < 2) {
        unsigned d0 = pack_bf16(acc[0] * LOG2E, acc[1] * LOG2E);
        unsigned d1 = pack_bf16(acc[2] * LOG2E, acc[3] * LOG2E);
        unsigned long long v = ((unsigned long long)d1 << 32) | d0;
        *(unsigned long long*)&qb[(size_t)(b * NN + n) * 8 + q4 * 4] = v;
    }
    // k rows
    acc = *(const f4v*)(bk + (q4 & 1) * 4);
    acc = __builtin_amdgcn_mfma_f32_16x16x32_bf16(A[0], Bv[0], acc, 0, 0, 0);
    acc = __builtin_amdgcn_mfma_f32_16x16x32_bf16(A[1], Bv[1], acc, 0, 0, 0);
    if (q4 >= 2) {
        unsigned d0 = pack_bf16(acc[0], acc[1]), d1 = pack_bf16(acc[2], acc[3]);
        unsigned long long v = ((unsigned long long)d1 << 32) | d0;
        *(unsigned long long*)&kb[(size_t)(b * NN + n) * 8 + (q4 - 2) * 4] = v;
    }
    // v rows -> vT[b][c][n]
#pragma unroll
    for (int tile = 1; tile < 5; tile++) {
        acc = *(const f4v*)(bv + (tile - 1) * 16 + q4 * 4);
        acc = __builtin_amdgcn_mfma_f32_16x16x32_bf16(A[tile * 2],     Bv[0], acc, 0, 0, 0);
        acc = __builtin_amdgcn_mfma_f32_16x16x32_bf16(A[tile * 2 + 1], Bv[1], acc, 0, 0, 0);
#pragma unroll
        for (int r = 0; r < 4; r++) {
            float other = DPP_F(acc[r], QP_X1);
            unsigned pkd = (lane & 1) ? pack_bf16(other, acc[r])
                                      : pack_bf16(acc[r], other);
            if (!(lane & 1)) {
                int row = (tile - 1) * 16 + q4 * 4 + r;
                *(unsigned*)&vT[(size_t)(b * 64 + row) * NN + n] = pkd;
            }
        }
    }
}

// ---------------------------------------------------------------------------
// K5: MFMA flash, split-K x8, 64 q/wave, DOUBLE-BUFFERED LDS V staging.
// V tile (8 KB) per kt loaded once per block (coalesced), stored pi-permuted
// so each lane's PV A-frag is one contiguous ds_read_b128. Double buffer ->
// ONE barrier per kt. pOT partials stored as bf16 in [s][b][c>>2][n][4c]
// layout: 16 coalesced b64 stores per wave.
// grid 512 = (split:8, b:4, qchunk:16 of 256). p = exp2(S) (no max-rescale:
// scores O(0.1), shift-invariant softmax; split partials sum directly).
__global__ __launch_bounds__(256, 2) void flash_k(const ushort* __restrict__ qb,
                                                  const ushort* __restrict__ kb,
                                                  const ushort* __restrict__ vT,
                                                  ushort* __restrict__ pOT,
                                                  float* __restrict__ pl) {
    __shared__ __align__(16) ushort Vlds[2 * 64 * 72]; // 18432 B
    int t = threadIdx.x;
    int lane = t & 63, w = t >> 6;
    int c15 = lane & 15, q4 = lane >> 4;
    int blk = blockIdx.x;
    int s = blk >> 6, b = (blk >> 4) & 3, q0 = (blk & 15) * 256;

    s8v qB[4];
#pragma unroll
    for (int g = 0; g < 4; g++) {
        i4v qa = (i4v){0, 0, 0, 0};
        if (q4 == 0)
            qa = *(const i4v*)(qb + (size_t)(b * NN + q0 + w * 64 + g * 16 + c15) * 8);
        qB[g] = __builtin_bit_cast(s8v, qa);
    }

    f4v accO[4][4];
#pragma unroll
    for (int g = 0; g < 4; g++)
#pragma unroll
        for (int nt = 0; nt < 4; nt++) accO[g][nt] = (f4v){0.f, 0.f, 0.f, 0.f};
    float lacc[4] = {0.f, 0.f, 0.f, 0.f};

    const ushort* kbb = kb + (size_t)b * NN * 8 + (size_t)c15 * 8;

    // staging role: thread t covers V row r, 16-k chunk chk
    int r = t >> 2, chk = t & 3;
    const ushort* vsrc = vT + (size_t)(b * 64 + r) * NN + chk * 16;
    int vdstoff = r * 72 + 32 * (chk >> 1) + 4 * (chk & 1);
    int vreadoff = c15 * 72 + 8 * q4;

    int kbase = s * 512;
    // preload K and V for kt0
    i4v bk_cur[4];
#pragma unroll
    for (int nt = 0; nt < 4; nt++)
        bk_cur[nt] = *(const i4v*)(kbb + (size_t)(kbase + nt * 16) * 8);
    i4v v0 = *(const i4v*)(vsrc + kbase);
    i4v v1 = *(const i4v*)(vsrc + kbase + 8);

    for (int kt = 0; kt < 8; kt++) {
        int k0 = kbase + kt * 64;
        // scatter-write tile kt into permuted LDS buffer kt&1
        ushort* vd = Vlds + (kt & 1) * 4608 + vdstoff;
        *(i2v*)(vd + 0)  = (i2v){v0[0], v0[1]};
        *(i2v*)(vd + 8)  = (i2v){v0[2], v0[3]};
        *(i2v*)(vd + 16) = (i2v){v1[0], v1[1]};
        *(i2v*)(vd + 24) = (i2v){v1[2], v1[3]};
        __syncthreads();                               // writes visible

        // PV A-frags: one contiguous b128 per (F,nt), shared by all 4 g
        const ushort* vb = Vlds + (kt & 1) * 4608 + vreadoff;
        i4v vA[2][4];
#pragma unroll
        for (int F = 0; F < 2; F++)
#pragma unroll
            for (int nt = 0; nt < 4; nt++)
                vA[F][nt] = *(const i4v*)(vb + nt * 16 * 72 + 32 * F);

        // prefetch next kt's V (global, coalesced) and K (broadcast)
        i4v bk_nxt[4];
        if (kt < 7) {
            v0 = *(const i4v*)(vsrc + k0 + 64);
            v1 = *(const i4v*)(vsrc + k0 + 64 + 8);
#pragma unroll
            for (int nt = 0; nt < 4; nt++)
                bk_nxt[nt] = *(const i4v*)(kbb + (size_t)(k0 + 64 + nt * 16) * 8);
        }

        // process q-groups in pairs (bounds register pressure)
#pragma unroll
        for (int gp = 0; gp < 2; gp++) {
            f4v z = (f4v){0.f, 0.f, 0.f, 0.f};
            f4v S[2][4];
#pragma unroll
            for (int gg = 0; gg < 2; gg++)
#pragma unroll
                for (int nt = 0; nt < 4; nt++)
                    S[gg][nt] = __builtin_amdgcn_mfma_f32_16x16x32_bf16(
                        __builtin_bit_cast(s8v, bk_cur[nt]), qB[gp * 2 + gg],
                        z, 0, 0, 0);

            s8v Bp[2][2];
#pragma unroll
            for (int gg = 0; gg < 2; gg++) {
                f4v p[4];
                float ps = 0.f;
#pragma unroll
                for (int nt = 0; nt < 4; nt++)
#pragma unroll
                    for (int rr = 0; rr < 4; rr++) {
                        p[nt][rr] = __builtin_amdgcn_exp2f(S[gg][nt][rr]);
                        ps += p[nt][rr];
                    }
#pragma unroll
                for (int F = 0; F < 2; F++) {
                    i4v bp;
                    bp[0] = (int)pack2(p[2 * F][0],     p[2 * F][1]);
                    bp[1] = (int)pack2(p[2 * F][2],     p[2 * F][3]);
                    bp[2] = (int)pack2(p[2 * F + 1][0], p[2 * F + 1][1]);
                    bp[3] = (int)pack2(p[2 * F + 1][2], p[2 * F + 1][3]);
                    Bp[gg][F] = __builtin_bit_cast(s8v, bp);
                }
                lacc[gp * 2 + gg] += ps;
            }

            // PV: O^T[c][q] += V^T * P
#pragma unroll
            for (int F = 0; F < 2; F++)
#pragma unroll
                for (int gg = 0; gg < 2; gg++)
#pragma unroll
                    for (int nt = 0; nt < 4; nt++)
                        accO[gp * 2 + gg][nt] =
                            __builtin_amdgcn_mfma_f32_16x16x32_bf16(
                                __builtin_bit_cast(s8v, vA[F][nt]), Bp[gg][F],
                                accO[gp * 2 + gg][nt], 0, 0, 0);
        }
        if (kt < 7) {
#pragma unroll
            for (int nt = 0; nt < 4; nt++) bk_cur[nt] = bk_nxt[nt];
        }
    }

    // one-time cross-lane l reduction (lanes sharing q: xor 16, 32)
#pragma unroll
    for (int g = 0; g < 4; g++) {
        lacc[g] += __shfl_xor(lacc[g], 16);
        lacc[g] += __shfl_xor(lacc[g], 32);
    }

    // store bf16 O^T partials [s][b][cg][n][4c] (coalesced b64), l
#pragma unroll
    for (int g = 0; g < 4; g++) {
        int qg = q0 + w * 64 + g * 16 + c15;
#pragma unroll
        for (int nt = 0; nt < 4; nt++) {
            int cg = nt * 4 + q4;
            u2v d;
            d[0] = pack2(accO[g][nt][0], accO[g][nt][1]);
            d[1] = pack2(accO[g][nt][2], accO[g][nt][3]);
            *(u2v*)&pOT[((size_t)((s * 4 + b) * 16 + cg) * NN + qg) * 4] = d;
        }
        if (q4 == 0)
            pl[(size_t)(s * 4 + b) * NN + qg] = lacc[g];
    }
}

// ---------------------------------------------------------------------------
// K6: combine 8 bf16 split-K partials: out = gamma*O/L + cnn.
// grid 256 = (b:4, nchunk:64 of 64). pOT is [s][b][cg][n][4c] bf16.
// Thread (cl 0..15, nq 0..15): c rows cl*4..+3, n quad n0+nq*4..+3.
__global__ __launch_bounds__(256) void comb_k(const ushort* __restrict__ pOT,
                                              const float* __restrict__ pl,
                                              const float* __restrict__ cnn,
                                              const float* __restrict__ gamma,
                                              float* __restrict__ out) {
    int t = threadIdx.x;
    int b = blockIdx.x >> 6, n0 = (blockIdx.x & 63) * 64;
    int nq = t & 15, cl = t >> 4;
    int n = n0 + nq * 4;
    f4v L = (f4v){0.f, 0.f, 0.f, 0.f};
#pragma unroll
    for (int s = 0; s < 8; s++)
        L += *(const f4v*)&pl[(size_t)(s * 4 + b) * NN + n];
    float g = *gamma;
    f4v rv;
#pragma unroll
    for (int j = 0; j < 4; j++) rv[j] = g / L[j];

    f4v Oc[4];                                        // [cc] components = j
#pragma unroll
    for (int cc = 0; cc < 4; cc++) Oc[cc] = (f4v){0.f, 0.f, 0.f, 0.f};
#pragma unroll
    for (int s = 0; s < 8; s++) {
        const ushort* src = pOT + ((size_t)((s * 4 + b) * 16 + cl) * NN + n) * 4;
        i4v a  = *(const i4v*)src;                    // n+0,n+1 x cc0..3
        i4v bb = *(const i4v*)(src + 8);              // n+2,n+3 x cc0..3
        Oc[0][0] += blo(a[0]);  Oc[1][0] += bhi(a[0]);
        Oc[2][0] += blo(a[1]);  Oc[3][0] += bhi(a[1]);
        Oc[0][1] += blo(a[2]);  Oc[1][1] += bhi(a[2]);
        Oc[2][1] += blo(a[3]);  Oc[3][1] += bhi(a[3]);
        Oc[0][2] += blo(bb[0]); Oc[1][2] += bhi(bb[0]);
        Oc[2][2] += blo(bb[1]); Oc[3][2] += bhi(bb[1]);
        Oc[0][3] += blo(bb[2]); Oc[1][3] += bhi(bb[2]);
        Oc[2][3] += blo(bb[3]); Oc[3][3] += bhi(bb[3]);
    }
#pragma unroll
    for (int cc = 0; cc < 4; cc++) {
        size_t gi = (size_t)(b * 64 + cl * 4 + cc) * NN + n;
        f4v cv = *(const f4v*)&cnn[gi];
        *(f4v*)&out[gi] = Oc[cc] * rv + cv;
    }
}

// ---------------------------------------------------------------------------
extern "C" void kernel_launch(void* const* d_in, const int* in_sizes, int n_in,
                              void* d_out, int out_size, void* d_ws, size_t ws_size,
                              hipStream_t stream) {
    const float* cnn  = (const float*)d_in[0];
    const float* vit  = (const float*)d_in[1];
    const float* Wq   = (const float*)d_in[2];
    const float* bq   = (const float*)d_in[3];
    const float* Wk   = (const float*)d_in[4];
    const float* bk   = (const float*)d_in[5];
    const float* Wv   = (const float*)d_in[6];
    const float* bv   = (const float*)d_in[7];
    const float* gam  = (const float*)d_in[8];
    const float* gcnn = (const float*)d_in[9];
    const float* gvit = (const float*)d_in[10];
    float* out = (float*)d_out;

    float* ws = (float*)d_ws;
    // pOT (bf16, 8 splits, 16 MB) aliases part (first 4 MB) — part is
    // consumed by gred_k before flash_k writes pOT.
    ushort* pOT   = (ushort*)ws;
    float*  part  = ws;
    float*  G     = ws + 8388608;            // 32768 f
    ushort* WeffB = (ushort*)(ws + 8421376); // 20480 bf16
    ushort* qb    = (ushort*)(ws + 8431616); // 131072 bf16
    ushort* kb    = (ushort*)(ws + 8497152);
    ushort* vT    = (ushort*)(ws + 8562688); // 1048576 bf16
    float*  pl    = ws + 9086976;            // 131072 f

    gram_k <<<256, 256, 0, stream>>>(cnn, vit, part);
    gred_k <<<512, 64,  0, stream>>>(part, G);
    weff_k <<<20,  256, 0, stream>>>(G, Wq, Wk, Wv, gcnn, gvit, WeffB);
    qkv_k  <<<256, 256, 0, stream>>>(cnn, vit, WeffB, bq, bk, bv, qb, kb, vT);
    flash_k<<<512, 256, 0, stream>>>(qb, kb, vT, pOT, pl);
    comb_k <<<256, 256, 0, stream>>>(pOT, pl, cnn, gam, out);
}